// Round 2
// baseline (903.940 us; speedup 1.0000x reference)
//
#include <hip/hip_runtime.h>
#include <hip/hip_fp16.h>

#define T_TOK 2048
#define H_DIM 2048
#define E_NUM 64
#define TOPK  8
#define I_DIM 768

#define BK   32
#define LDK  40   // padded LDS row length (fp16 elems): 80B rows, 16B aligned, ~2-way banks

using f16x8 = __attribute__((ext_vector_type(8))) _Float16;
using f16x4 = __attribute__((ext_vector_type(4))) _Float16;
using f32x4 = __attribute__((ext_vector_type(4))) float;

// ---------------- X fp32 -> fp16 ----------------
__global__ void convert_x_kernel(const float* __restrict__ x, _Float16* __restrict__ xh, int n) {
    int i = (blockIdx.x * blockDim.x + threadIdx.x) * 4;
    if (i < n) {
        float4 v = *reinterpret_cast<const float4*>(x + i);
        f16x4 o;
        o[0] = (_Float16)v.x; o[1] = (_Float16)v.y; o[2] = (_Float16)v.z; o[3] = (_Float16)v.w;
        *reinterpret_cast<f16x4*>(xh + i) = o;
    }
}

// ---------------- router + top-k (fp32, one wave per token) ----------------
__global__ __launch_bounds__(64) void router_topk_kernel(
        const float* __restrict__ x, const float* __restrict__ wr,
        int* __restrict__ topk_i, float* __restrict__ topk_w) {
    __shared__ float xs[H_DIM];
    int t = blockIdx.x;
    int lane = threadIdx.x;
    const float* xp = x + (size_t)t * H_DIM;
    for (int i = lane * 4; i < H_DIM; i += 64 * 4) {
        *reinterpret_cast<float4*>(xs + i) = *reinterpret_cast<const float4*>(xp + i);
    }
    __syncthreads();
    const float* wp = wr + (size_t)lane * H_DIM;
    float acc = 0.f;
    for (int h = 0; h < H_DIM; h += 4) {
        float4 w = *reinterpret_cast<const float4*>(wp + h);
        acc += xs[h] * w.x + xs[h + 1] * w.y + xs[h + 2] * w.z + xs[h + 3] * w.w;
    }
    // softmax over 64 lanes (lane == expert)
    float m = acc;
    #pragma unroll
    for (int d = 32; d; d >>= 1) m = fmaxf(m, __shfl_xor(m, d));
    float p = __expf(acc - m);
    float s = p;
    #pragma unroll
    for (int d = 32; d; d >>= 1) s += __shfl_xor(s, d);
    p /= s;
    // iterative top-8 (argmax w/ min-index tiebreak, matching lax.top_k)
    float selv[TOPK]; int seli[TOPK];
    float cur = p;
    #pragma unroll
    for (int k = 0; k < TOPK; ++k) {
        float v = cur; int idx = lane;
        #pragma unroll
        for (int d = 32; d; d >>= 1) {
            float ov = __shfl_xor(v, d); int oi = __shfl_xor(idx, d);
            if (ov > v || (ov == v && oi < idx)) { v = ov; idx = oi; }
        }
        selv[k] = v; seli[k] = idx;
        if (lane == idx) cur = -1.f;
    }
    float sum = 0.f;
    #pragma unroll
    for (int k = 0; k < TOPK; ++k) sum += selv[k];
    if (lane == 0) {
        #pragma unroll
        for (int k = 0; k < TOPK; ++k) {
            topk_i[t * TOPK + k] = seli[k];
            topk_w[t * TOPK + k] = selv[k] / sum;
        }
    }
}

// ---------------- expert histogram / scan / scatter ----------------
__global__ void count_kernel(const int* __restrict__ topk_i, int* __restrict__ counts) {
    int i = blockIdx.x * blockDim.x + threadIdx.x;
    if (i < T_TOK * TOPK) atomicAdd(&counts[topk_i[i]], 1);
}

__global__ __launch_bounds__(64) void scan_kernel(const int* __restrict__ counts,
                                                  int* __restrict__ offsets,
                                                  int* __restrict__ cursor) {
    __shared__ int c[E_NUM];
    int e = threadIdx.x;
    c[e] = counts[e];
    __syncthreads();
    int off = 0;
    for (int j = 0; j < e; ++j) off += c[j];
    offsets[e] = off;
    cursor[e] = off;
}

__global__ void scatter_kernel(const int* __restrict__ topk_i, const float* __restrict__ topk_w,
                               int* __restrict__ cursor,
                               int* __restrict__ token_list, float* __restrict__ weight_list) {
    int i = blockIdx.x * blockDim.x + threadIdx.x;
    if (i < T_TOK * TOPK) {
        int e = topk_i[i];
        int pos = atomicAdd(&cursor[e], 1);   // cursor pre-initialized to offsets
        token_list[pos] = i >> 3;
        weight_list[pos] = topk_w[i];
    }
}

// ---------------- gate/up fused GEMM: h = silu(X wg^T) * (X wu^T), fp16 out ----------------
// tile: BM=128 (slots), BN=64 (features), BK=32. 4 waves (2x2), dual accumulators.
__global__ __launch_bounds__(256) void gateup_kernel(
        const _Float16* __restrict__ xh, const float* __restrict__ wg,
        const float* __restrict__ wu, const int* __restrict__ offsets,
        const int* __restrict__ counts, const int* __restrict__ token_list,
        _Float16* __restrict__ hbuf) {
    int e = blockIdx.x;
    int n_e = counts[e];
    int m_base = blockIdx.z * 128;
    if (m_base >= n_e) return;
    int off_e = offsets[e];
    int n_base = blockIdx.y * 64;
    // per-expert weight bases (THE round-1 bug: these offsets were missing)
    const float* wg_e = wg + (size_t)e * I_DIM * H_DIM;
    const float* wu_e = wu + (size_t)e * I_DIM * H_DIM;

    __shared__ _Float16 As[128 * LDK];
    __shared__ _Float16 Bg[64 * LDK];
    __shared__ _Float16 Bu[64 * LDK];
    __shared__ int toks[128];

    int tid = threadIdx.x;
    if (tid < 128) {
        int m = m_base + tid;
        toks[tid] = token_list[off_e + min(m, n_e - 1)];
    }
    __syncthreads();

    // A staging: 2 tasks/thread (rows tid>>2 and 64+tid>>2, seg tid&3, 8 halves each)
    int arow = tid >> 2;
    int aseg = tid & 3;
    const _Float16* asrc0 = xh + (size_t)toks[arow] * H_DIM + aseg * 8;
    const _Float16* asrc1 = xh + (size_t)toks[64 + arow] * H_DIM + aseg * 8;
    _Float16* adst0 = As + arow * LDK + aseg * 8;
    _Float16* adst1 = As + (64 + arow) * LDK + aseg * 8;

    f32x4 accg[4][2], accu[4][2];
    #pragma unroll
    for (int i = 0; i < 4; ++i)
        #pragma unroll
        for (int j = 0; j < 2; ++j) { accg[i][j] = (f32x4)0.f; accu[i][j] = (f32x4)0.f; }

    int wave = tid >> 6, lane = tid & 63;
    int wm = wave >> 1, wn = wave & 1;

    for (int k0 = 0; k0 < H_DIM; k0 += BK) {
        __syncthreads();
        *reinterpret_cast<f16x8*>(adst0) = *reinterpret_cast<const f16x8*>(asrc0 + k0);
        *reinterpret_cast<f16x8*>(adst1) = *reinterpret_cast<const f16x8*>(asrc1 + k0);
        #pragma unroll
        for (int j = 0; j < 4; ++j) {
            int task = tid + 256 * j;
            int mat = task >> 9;
            int r = (task >> 3) & 63;
            int seg = task & 7;
            const float* src = (mat ? wu_e : wg_e) + (size_t)(n_base + r) * H_DIM + k0 + seg * 4;
            float4 v = *reinterpret_cast<const float4*>(src);
            f16x4 o;
            o[0] = (_Float16)v.x; o[1] = (_Float16)v.y; o[2] = (_Float16)v.z; o[3] = (_Float16)v.w;
            _Float16* dst = (mat ? Bu : Bg) + r * LDK + seg * 4;
            *reinterpret_cast<f16x4*>(dst) = o;
        }
        __syncthreads();

        f16x8 a[4], bg[2], bu[2];
        #pragma unroll
        for (int fm = 0; fm < 4; ++fm) {
            int row = wm * 64 + fm * 16 + (lane & 15);
            a[fm] = *reinterpret_cast<const f16x8*>(As + row * LDK + (lane >> 4) * 8);
        }
        #pragma unroll
        for (int fn = 0; fn < 2; ++fn) {
            int row = wn * 32 + fn * 16 + (lane & 15);
            bg[fn] = *reinterpret_cast<const f16x8*>(Bg + row * LDK + (lane >> 4) * 8);
            bu[fn] = *reinterpret_cast<const f16x8*>(Bu + row * LDK + (lane >> 4) * 8);
        }
        #pragma unroll
        for (int fm = 0; fm < 4; ++fm)
            #pragma unroll
            for (int fn = 0; fn < 2; ++fn) {
                accg[fm][fn] = __builtin_amdgcn_mfma_f32_16x16x32_f16(a[fm], bg[fn], accg[fm][fn], 0, 0, 0);
                accu[fm][fn] = __builtin_amdgcn_mfma_f32_16x16x32_f16(a[fm], bu[fn], accu[fm][fn], 0, 0, 0);
            }
    }

    // epilogue: h = silu(g) * u  (C/D layout: col=lane&15, row=(lane>>4)*4+reg)
    #pragma unroll
    for (int fm = 0; fm < 4; ++fm) {
        #pragma unroll
        for (int reg = 0; reg < 4; ++reg) {
            int row = wm * 64 + fm * 16 + (lane >> 4) * 4 + reg;
            int m = m_base + row;
            if (m < n_e) {
                #pragma unroll
                for (int fn = 0; fn < 2; ++fn) {
                    int col = wn * 32 + fn * 16 + (lane & 15);
                    float g = accg[fm][fn][reg];
                    float u = accu[fm][fn][reg];
                    float hv = g * u / (1.f + __expf(-g));
                    hbuf[(size_t)(off_e + m) * I_DIM + n_base + col] = (_Float16)hv;
                }
            }
        }
    }
}

// ---------------- down GEMM: out[token] += w_slot * (h wd^T) ----------------
// tile: BM=128 (slots), BN=128 (H cols), BK=32. 4 waves (2x2), atomic fp32 combine.
__global__ __launch_bounds__(256) void down_kernel(
        const _Float16* __restrict__ hbuf, const float* __restrict__ wd,
        const int* __restrict__ offsets, const int* __restrict__ counts,
        const int* __restrict__ token_list, const float* __restrict__ weight_list,
        float* __restrict__ out) {
    int e = blockIdx.x;
    int n_e = counts[e];
    int m_base = blockIdx.z * 128;
    if (m_base >= n_e) return;
    int off_e = offsets[e];
    int n_base = blockIdx.y * 128;
    // per-expert weight base (THE round-1 bug: this offset was missing)
    const float* wd_e = wd + (size_t)e * H_DIM * I_DIM;

    __shared__ _Float16 As[128 * LDK];
    __shared__ _Float16 Bs[128 * LDK];

    int tid = threadIdx.x;
    int arow = tid >> 2;
    int aseg = tid & 3;
    int am0 = min(m_base + arow, n_e - 1);
    int am1 = min(m_base + 64 + arow, n_e - 1);
    const _Float16* asrc0 = hbuf + (size_t)(off_e + am0) * I_DIM + aseg * 8;
    const _Float16* asrc1 = hbuf + (size_t)(off_e + am1) * I_DIM + aseg * 8;
    _Float16* adst0 = As + arow * LDK + aseg * 8;
    _Float16* adst1 = As + (64 + arow) * LDK + aseg * 8;

    f32x4 acc[4][4];
    #pragma unroll
    for (int i = 0; i < 4; ++i)
        #pragma unroll
        for (int j = 0; j < 4; ++j) acc[i][j] = (f32x4)0.f;

    int wave = tid >> 6, lane = tid & 63;
    int wm = wave >> 1, wn = wave & 1;

    for (int k0 = 0; k0 < I_DIM; k0 += BK) {
        __syncthreads();
        *reinterpret_cast<f16x8*>(adst0) = *reinterpret_cast<const f16x8*>(asrc0 + k0);
        *reinterpret_cast<f16x8*>(adst1) = *reinterpret_cast<const f16x8*>(asrc1 + k0);
        #pragma unroll
        for (int j = 0; j < 4; ++j) {
            int task = tid + 256 * j;
            int r = task >> 3;
            int seg = task & 7;
            const float* src = wd_e + (size_t)(n_base + r) * I_DIM + k0 + seg * 4;
            float4 v = *reinterpret_cast<const float4*>(src);
            f16x4 o;
            o[0] = (_Float16)v.x; o[1] = (_Float16)v.y; o[2] = (_Float16)v.z; o[3] = (_Float16)v.w;
            *reinterpret_cast<f16x4*>(Bs + r * LDK + seg * 4) = o;
        }
        __syncthreads();

        f16x8 a[4], b[4];
        #pragma unroll
        for (int fm = 0; fm < 4; ++fm) {
            int row = wm * 64 + fm * 16 + (lane & 15);
            a[fm] = *reinterpret_cast<const f16x8*>(As + row * LDK + (lane >> 4) * 8);
        }
        #pragma unroll
        for (int fn = 0; fn < 4; ++fn) {
            int row = wn * 64 + fn * 16 + (lane & 15);
            b[fn] = *reinterpret_cast<const f16x8*>(Bs + row * LDK + (lane >> 4) * 8);
        }
        #pragma unroll
        for (int fm = 0; fm < 4; ++fm)
            #pragma unroll
            for (int fn = 0; fn < 4; ++fn)
                acc[fm][fn] = __builtin_amdgcn_mfma_f32_16x16x32_f16(a[fm], b[fn], acc[fm][fn], 0, 0, 0);
    }

    #pragma unroll
    for (int fm = 0; fm < 4; ++fm) {
        #pragma unroll
        for (int reg = 0; reg < 4; ++reg) {
            int m = m_base + wm * 64 + fm * 16 + (lane >> 4) * 4 + reg;
            if (m < n_e) {
                int slot = off_e + m;
                int t = token_list[slot];
                float w = weight_list[slot];
                float* orow = out + (size_t)t * H_DIM + n_base;
                #pragma unroll
                for (int fn = 0; fn < 4; ++fn) {
                    int col = wn * 64 + fn * 16 + (lane & 15);
                    atomicAdd(orow + col, w * acc[fm][fn][reg]);
                }
            }
        }
    }
}

extern "C" void kernel_launch(void* const* d_in, const int* in_sizes, int n_in,
                              void* d_out, int out_size, void* d_ws, size_t ws_size,
                              hipStream_t stream) {
    const float* x  = (const float*)d_in[0];
    const float* wr = (const float*)d_in[1];
    const float* wg = (const float*)d_in[2];
    const float* wu = (const float*)d_in[3];
    const float* wd = (const float*)d_in[4];
    float* out = (float*)d_out;

    char* p = (char*)d_ws;
    auto carve = [&](size_t bytes) { char* q = p; p += (bytes + 255) & ~255ULL; return q; };
    _Float16* xh     = (_Float16*)carve((size_t)T_TOK * H_DIM * 2);       // 8 MB
    _Float16* hbuf   = (_Float16*)carve((size_t)T_TOK * TOPK * I_DIM * 2);// 24 MB
    int*   topk_i    = (int*)  carve(T_TOK * TOPK * 4);
    float* topk_w    = (float*)carve(T_TOK * TOPK * 4);
    int*   tlist     = (int*)  carve(T_TOK * TOPK * 4);
    float* wlist     = (float*)carve(T_TOK * TOPK * 4);
    int*   counts    = (int*)  carve(E_NUM * 4);
    int*   offsets   = (int*)  carve(E_NUM * 4);
    int*   cursor    = (int*)  carve(E_NUM * 4);

    hipMemsetAsync(d_out, 0, (size_t)out_size * 4, stream);
    hipMemsetAsync(counts, 0, E_NUM * 4, stream);

    convert_x_kernel<<<(T_TOK * H_DIM) / (256 * 4), 256, 0, stream>>>(x, xh, T_TOK * H_DIM);
    router_topk_kernel<<<T_TOK, 64, 0, stream>>>(x, wr, topk_i, topk_w);
    count_kernel<<<(T_TOK * TOPK) / 256, 256, 0, stream>>>(topk_i, counts);
    scan_kernel<<<1, 64, 0, stream>>>(counts, offsets, cursor);
    scatter_kernel<<<(T_TOK * TOPK) / 256, 256, 0, stream>>>(topk_i, topk_w, cursor, tlist, wlist);
    gateup_kernel<<<dim3(E_NUM, I_DIM / 64, 16), 256, 0, stream>>>(xh, wg, wu, offsets, counts, tlist, hbuf);
    down_kernel<<<dim3(E_NUM, H_DIM / 128, 16), 256, 0, stream>>>(hbuf, wd, offsets, counts, tlist, wlist, out);
}

// Round 4
// 832.286 us; speedup vs baseline: 1.0861x; 1.0861x over previous
//
#include <hip/hip_runtime.h>
#include <hip/hip_fp16.h>

#define T_TOK 2048
#define H_DIM 2048
#define E_NUM 64
#define TOPK  8
#define I_DIM 768

#define BK   32
#define LDK  40   // padded LDS row (fp16 elems): 80B rows -> 2-way bank alias (free, m136)

#define GU_MT 16
#define GU_NT (I_DIM / 64)            // 12
#define GU_NWG (GU_MT * GU_NT * E_NUM)  // 12288, %8==0
#define DN_MT 16
#define DN_NT (H_DIM / 128)           // 16
#define DN_NWG (DN_MT * DN_NT * E_NUM)  // 16384, %8==0

using f16x8 = __attribute__((ext_vector_type(8))) _Float16;
using f16x4 = __attribute__((ext_vector_type(4))) _Float16;
using f16x2 = __attribute__((ext_vector_type(2))) _Float16;
using f32x4 = __attribute__((ext_vector_type(4))) float;

__device__ __forceinline__ f16x4 cvt4(float4 v) {
    f16x2 lo = __builtin_bit_cast(f16x2, __builtin_amdgcn_cvt_pkrtz(v.x, v.y));
    f16x2 hi = __builtin_bit_cast(f16x2, __builtin_amdgcn_cvt_pkrtz(v.z, v.w));
    f16x4 o;
    o[0] = lo[0]; o[1] = lo[1]; o[2] = hi[0]; o[3] = hi[1];
    return o;
}

// ---------------- X fp32 -> fp16 ----------------
__global__ void convert_x_kernel(const float* __restrict__ x, _Float16* __restrict__ xh, int n) {
    int i = (blockIdx.x * blockDim.x + threadIdx.x) * 4;
    if (i < n) {
        float4 v = *reinterpret_cast<const float4*>(x + i);
        *reinterpret_cast<f16x4*>(xh + i) = cvt4(v);
    }
}

// ---------------- router + top-k (fp32, one wave per token) ----------------
__global__ __launch_bounds__(64) void router_topk_kernel(
        const float* __restrict__ x, const float* __restrict__ wr,
        int* __restrict__ topk_i, float* __restrict__ topk_w) {
    __shared__ float xs[H_DIM];
    int t = blockIdx.x;
    int lane = threadIdx.x;
    const float* xp = x + (size_t)t * H_DIM;
    for (int i = lane * 4; i < H_DIM; i += 64 * 4) {
        *reinterpret_cast<float4*>(xs + i) = *reinterpret_cast<const float4*>(xp + i);
    }
    __syncthreads();
    const float* wp = wr + (size_t)lane * H_DIM;
    float acc = 0.f;
    for (int h = 0; h < H_DIM; h += 4) {
        float4 w = *reinterpret_cast<const float4*>(wp + h);
        acc += xs[h] * w.x + xs[h + 1] * w.y + xs[h + 2] * w.z + xs[h + 3] * w.w;
    }
    float m = acc;
    #pragma unroll
    for (int d = 32; d; d >>= 1) m = fmaxf(m, __shfl_xor(m, d));
    float p = __expf(acc - m);
    float s = p;
    #pragma unroll
    for (int d = 32; d; d >>= 1) s += __shfl_xor(s, d);
    p /= s;
    float selv[TOPK]; int seli[TOPK];
    float cur = p;
    #pragma unroll
    for (int k = 0; k < TOPK; ++k) {
        float v = cur; int idx = lane;
        #pragma unroll
        for (int d = 32; d; d >>= 1) {
            float ov = __shfl_xor(v, d); int oi = __shfl_xor(idx, d);
            if (ov > v || (ov == v && oi < idx)) { v = ov; idx = oi; }
        }
        selv[k] = v; seli[k] = idx;
        if (lane == idx) cur = -1.f;
    }
    float sum = 0.f;
    #pragma unroll
    for (int k = 0; k < TOPK; ++k) sum += selv[k];
    if (lane == 0) {
        #pragma unroll
        for (int k = 0; k < TOPK; ++k) {
            topk_i[t * TOPK + k] = seli[k];
            topk_w[t * TOPK + k] = selv[k] / sum;
        }
    }
}

// ---------------- expert histogram / scan / scatter ----------------
__global__ void count_kernel(const int* __restrict__ topk_i, int* __restrict__ counts) {
    int i = blockIdx.x * blockDim.x + threadIdx.x;
    if (i < T_TOK * TOPK) atomicAdd(&counts[topk_i[i]], 1);
}

__global__ __launch_bounds__(64) void scan_kernel(const int* __restrict__ counts,
                                                  int* __restrict__ offsets,
                                                  int* __restrict__ cursor) {
    __shared__ int c[E_NUM];
    int e = threadIdx.x;
    c[e] = counts[e];
    __syncthreads();
    int off = 0;
    for (int j = 0; j < e; ++j) off += c[j];
    offsets[e] = off;
    cursor[e] = off;
}

__global__ void scatter_kernel(const int* __restrict__ topk_i, const float* __restrict__ topk_w,
                               int* __restrict__ cursor,
                               int* __restrict__ token_list, float* __restrict__ weight_list) {
    int i = blockIdx.x * blockDim.x + threadIdx.x;
    if (i < T_TOK * TOPK) {
        int e = topk_i[i];
        int pos = atomicAdd(&cursor[e], 1);
        token_list[pos] = i >> 3;
        weight_list[pos] = topk_w[i];
    }
}

// ---------------- gate/up fused GEMM, 2-phase dbuf pipeline ----------------
// tile BM=128 slots x BN=64 feats (gate+up), BK=32. 4 waves 2x2.
// grid: 1D, XCD-chunked swizzle, m-tile fastest (weight tiles L2-hit across m).
__global__ __launch_bounds__(256) void gateup_kernel(
        const _Float16* __restrict__ xh, const float* __restrict__ wg,
        const float* __restrict__ wu, const int* __restrict__ offsets,
        const int* __restrict__ counts, const int* __restrict__ token_list,
        _Float16* __restrict__ hbuf) {
    int orig = blockIdx.x;
    int w = (orig & 7) * (GU_NWG / 8) + (orig >> 3);   // XCD-chunked (bijective: %8==0)
    int mt = w & (GU_MT - 1);
    int nt = (w / GU_MT) % GU_NT;
    int e  = w / (GU_MT * GU_NT);
    int n_e = counts[e];
    int m_base = mt * 128;
    if (m_base >= n_e) return;
    int off_e = offsets[e];
    int n_base = nt * 64;
    const float* wg_e = wg + (size_t)e * I_DIM * H_DIM;
    const float* wu_e = wu + (size_t)e * I_DIM * H_DIM;

    __shared__ _Float16 As[2][128 * LDK];
    __shared__ _Float16 Bg[2][64 * LDK];
    __shared__ _Float16 Bu[2][64 * LDK];
    __shared__ int toks[128];

    int tid = threadIdx.x;
    if (tid < 128) toks[tid] = token_list[off_e + min(m_base + tid, n_e - 1)];
    __syncthreads();

    // ---- staging addresses (k0-independent, hoisted) ----
    int arow = tid >> 2, aseg = tid & 3;
    const _Float16* asrc0 = xh + (size_t)toks[arow] * H_DIM + aseg * 8;
    const _Float16* asrc1 = xh + (size_t)toks[64 + arow] * H_DIM + aseg * 8;
    int ado0 = arow * LDK + aseg * 8;
    int ado1 = (64 + arow) * LDK + aseg * 8;
    int br = tid >> 3, bseg = tid & 7;                  // B rows 0..31 (+32), 4-float segs
    const float* bsg0 = wg_e + (size_t)(n_base + br) * H_DIM + bseg * 4;
    const float* bsg1 = bsg0 + (size_t)32 * H_DIM;
    const float* bsu0 = wu_e + (size_t)(n_base + br) * H_DIM + bseg * 4;
    const float* bsu1 = bsu0 + (size_t)32 * H_DIM;
    int bdo0 = br * LDK + bseg * 4;
    int bdo1 = (32 + br) * LDK + bseg * 4;

    // ---- fragment LDS offsets ----
    int wave = tid >> 6, lane = tid & 63;
    int wm = wave >> 1, wn = wave & 1;
    int afr[4], bfr[2];
    #pragma unroll
    for (int fm = 0; fm < 4; ++fm)
        afr[fm] = (wm * 64 + fm * 16 + (lane & 15)) * LDK + (lane >> 4) * 8;
    #pragma unroll
    for (int fn = 0; fn < 2; ++fn)
        bfr[fn] = (wn * 32 + fn * 16 + (lane & 15)) * LDK + (lane >> 4) * 8;

    f32x4 accg[4][2], accu[4][2];
    #pragma unroll
    for (int i = 0; i < 4; ++i)
        #pragma unroll
        for (int j = 0; j < 2; ++j) { accg[i][j] = (f32x4)0.f; accu[i][j] = (f32x4)0.f; }

    auto compute = [&](int b) {
        f16x8 a[4], g[2], u[2];
        #pragma unroll
        for (int fm = 0; fm < 4; ++fm) a[fm] = *reinterpret_cast<const f16x8*>(&As[b][afr[fm]]);
        #pragma unroll
        for (int fn = 0; fn < 2; ++fn) {
            g[fn] = *reinterpret_cast<const f16x8*>(&Bg[b][bfr[fn]]);
            u[fn] = *reinterpret_cast<const f16x8*>(&Bu[b][bfr[fn]]);
        }
        #pragma unroll
        for (int fm = 0; fm < 4; ++fm)
            #pragma unroll
            for (int fn = 0; fn < 2; ++fn) {
                accg[fm][fn] = __builtin_amdgcn_mfma_f32_16x16x32_f16(a[fm], g[fn], accg[fm][fn], 0, 0, 0);
                accu[fm][fn] = __builtin_amdgcn_mfma_f32_16x16x32_f16(a[fm], u[fn], accu[fm][fn], 0, 0, 0);
            }
    };

    // ---- prologue: stage tile 0 ----
    {
        f16x8 ra0 = *reinterpret_cast<const f16x8*>(asrc0);
        f16x8 ra1 = *reinterpret_cast<const f16x8*>(asrc1);
        float4 rb0 = *reinterpret_cast<const float4*>(bsg0);
        float4 rb1 = *reinterpret_cast<const float4*>(bsg1);
        float4 rb2 = *reinterpret_cast<const float4*>(bsu0);
        float4 rb3 = *reinterpret_cast<const float4*>(bsu1);
        *reinterpret_cast<f16x8*>(&As[0][ado0]) = ra0;
        *reinterpret_cast<f16x8*>(&As[0][ado1]) = ra1;
        *reinterpret_cast<f16x4*>(&Bg[0][bdo0]) = cvt4(rb0);
        *reinterpret_cast<f16x4*>(&Bg[0][bdo1]) = cvt4(rb1);
        *reinterpret_cast<f16x4*>(&Bu[0][bdo0]) = cvt4(rb2);
        *reinterpret_cast<f16x4*>(&Bu[0][bdo1]) = cvt4(rb3);
    }
    __syncthreads();

    const int NT = H_DIM / BK;   // 64
    int cur = 0;
    for (int t = 0; t < NT - 1; ++t) {
        int kn = (t + 1) * BK;
        // T14: issue next-tile loads FIRST (latency hides under MFMA)
        f16x8 ra0 = *reinterpret_cast<const f16x8*>(asrc0 + kn);
        f16x8 ra1 = *reinterpret_cast<const f16x8*>(asrc1 + kn);
        float4 rb0 = *reinterpret_cast<const float4*>(bsg0 + kn);
        float4 rb1 = *reinterpret_cast<const float4*>(bsg1 + kn);
        float4 rb2 = *reinterpret_cast<const float4*>(bsu0 + kn);
        float4 rb3 = *reinterpret_cast<const float4*>(bsu1 + kn);
        compute(cur);
        // write-late into the other buffer
        *reinterpret_cast<f16x8*>(&As[cur ^ 1][ado0]) = ra0;
        *reinterpret_cast<f16x8*>(&As[cur ^ 1][ado1]) = ra1;
        *reinterpret_cast<f16x4*>(&Bg[cur ^ 1][bdo0]) = cvt4(rb0);
        *reinterpret_cast<f16x4*>(&Bg[cur ^ 1][bdo1]) = cvt4(rb1);
        *reinterpret_cast<f16x4*>(&Bu[cur ^ 1][bdo0]) = cvt4(rb2);
        *reinterpret_cast<f16x4*>(&Bu[cur ^ 1][bdo1]) = cvt4(rb3);
        __syncthreads();
        cur ^= 1;
    }
    compute(cur);

    // ---- epilogue: h = silu(g)*u ----
    #pragma unroll
    for (int fm = 0; fm < 4; ++fm) {
        #pragma unroll
        for (int reg = 0; reg < 4; ++reg) {
            int row = wm * 64 + fm * 16 + (lane >> 4) * 4 + reg;
            int m = m_base + row;
            if (m < n_e) {
                #pragma unroll
                for (int fn = 0; fn < 2; ++fn) {
                    int col = wn * 32 + fn * 16 + (lane & 15);
                    float g = accg[fm][fn][reg];
                    float u = accu[fm][fn][reg];
                    float hv = g * u / (1.f + __expf(-g));
                    hbuf[(size_t)(off_e + m) * I_DIM + n_base + col] = (_Float16)hv;
                }
            }
        }
    }
}

// ---------------- down GEMM, 2-phase dbuf pipeline ----------------
// tile BM=128 slots x BN=128 H-cols, BK=32. 4 waves 2x2. atomic fp32 combine.
__global__ __launch_bounds__(256) void down_kernel(
        const _Float16* __restrict__ hbuf, const float* __restrict__ wd,
        const int* __restrict__ offsets, const int* __restrict__ counts,
        const int* __restrict__ token_list, const float* __restrict__ weight_list,
        float* __restrict__ out) {
    int orig = blockIdx.x;
    int w = (orig & 7) * (DN_NWG / 8) + (orig >> 3);
    int mt = w & (DN_MT - 1);
    int nt = (w / DN_MT) % DN_NT;
    int e  = w / (DN_MT * DN_NT);
    int n_e = counts[e];
    int m_base = mt * 128;
    if (m_base >= n_e) return;
    int off_e = offsets[e];
    int n_base = nt * 128;
    const float* wd_e = wd + (size_t)e * H_DIM * I_DIM;

    __shared__ _Float16 As[2][128 * LDK];
    __shared__ _Float16 Bs[2][128 * LDK];

    int tid = threadIdx.x;
    int arow = tid >> 2, aseg = tid & 3;
    int am0 = min(m_base + arow, n_e - 1);
    int am1 = min(m_base + 64 + arow, n_e - 1);
    const _Float16* asrc0 = hbuf + (size_t)(off_e + am0) * I_DIM + aseg * 8;
    const _Float16* asrc1 = hbuf + (size_t)(off_e + am1) * I_DIM + aseg * 8;
    int ado0 = arow * LDK + aseg * 8;
    int ado1 = (64 + arow) * LDK + aseg * 8;
    int br = tid >> 3, bseg = tid & 7;                 // rows 0..31 step 32, 4 tasks
    const float* bs0 = wd_e + (size_t)(n_base + br) * I_DIM + bseg * 4;
    const float* bs1 = bs0 + (size_t)32 * I_DIM;
    const float* bs2 = bs0 + (size_t)64 * I_DIM;
    const float* bs3 = bs0 + (size_t)96 * I_DIM;
    int bdo0 = br * LDK + bseg * 4;
    int bdo1 = (32 + br) * LDK + bseg * 4;
    int bdo2 = (64 + br) * LDK + bseg * 4;
    int bdo3 = (96 + br) * LDK + bseg * 4;

    int wave = tid >> 6, lane = tid & 63;
    int wm = wave >> 1, wn = wave & 1;
    int afr[4], bfr[4];
    #pragma unroll
    for (int fm = 0; fm < 4; ++fm)
        afr[fm] = (wm * 64 + fm * 16 + (lane & 15)) * LDK + (lane >> 4) * 8;
    #pragma unroll
    for (int fn = 0; fn < 4; ++fn)
        bfr[fn] = (wn * 64 + fn * 16 + (lane & 15)) * LDK + (lane >> 4) * 8;

    f32x4 acc[4][4];
    #pragma unroll
    for (int i = 0; i < 4; ++i)
        #pragma unroll
        for (int j = 0; j < 4; ++j) acc[i][j] = (f32x4)0.f;

    auto compute = [&](int b) {
        f16x8 a[4], bb[4];
        #pragma unroll
        for (int fm = 0; fm < 4; ++fm) a[fm] = *reinterpret_cast<const f16x8*>(&As[b][afr[fm]]);
        #pragma unroll
        for (int fn = 0; fn < 4; ++fn) bb[fn] = *reinterpret_cast<const f16x8*>(&Bs[b][bfr[fn]]);
        #pragma unroll
        for (int fm = 0; fm < 4; ++fm)
            #pragma unroll
            for (int fn = 0; fn < 4; ++fn)
                acc[fm][fn] = __builtin_amdgcn_mfma_f32_16x16x32_f16(a[fm], bb[fn], acc[fm][fn], 0, 0, 0);
    };

    {
        f16x8 ra0 = *reinterpret_cast<const f16x8*>(asrc0);
        f16x8 ra1 = *reinterpret_cast<const f16x8*>(asrc1);
        float4 rb0 = *reinterpret_cast<const float4*>(bs0);
        float4 rb1 = *reinterpret_cast<const float4*>(bs1);
        float4 rb2 = *reinterpret_cast<const float4*>(bs2);
        float4 rb3 = *reinterpret_cast<const float4*>(bs3);
        *reinterpret_cast<f16x8*>(&As[0][ado0]) = ra0;
        *reinterpret_cast<f16x8*>(&As[0][ado1]) = ra1;
        *reinterpret_cast<f16x4*>(&Bs[0][bdo0]) = cvt4(rb0);
        *reinterpret_cast<f16x4*>(&Bs[0][bdo1]) = cvt4(rb1);
        *reinterpret_cast<f16x4*>(&Bs[0][bdo2]) = cvt4(rb2);
        *reinterpret_cast<f16x4*>(&Bs[0][bdo3]) = cvt4(rb3);
    }
    __syncthreads();

    const int NT = I_DIM / BK;   // 24
    int cur = 0;
    for (int t = 0; t < NT - 1; ++t) {
        int kn = (t + 1) * BK;
        f16x8 ra0 = *reinterpret_cast<const f16x8*>(asrc0 + kn);
        f16x8 ra1 = *reinterpret_cast<const f16x8*>(asrc1 + kn);
        float4 rb0 = *reinterpret_cast<const float4*>(bs0 + kn);
        float4 rb1 = *reinterpret_cast<const float4*>(bs1 + kn);
        float4 rb2 = *reinterpret_cast<const float4*>(bs2 + kn);
        float4 rb3 = *reinterpret_cast<const float4*>(bs3 + kn);
        compute(cur);
        *reinterpret_cast<f16x8*>(&As[cur ^ 1][ado0]) = ra0;
        *reinterpret_cast<f16x8*>(&As[cur ^ 1][ado1]) = ra1;
        *reinterpret_cast<f16x4*>(&Bs[cur ^ 1][bdo0]) = cvt4(rb0);
        *reinterpret_cast<f16x4*>(&Bs[cur ^ 1][bdo1]) = cvt4(rb1);
        *reinterpret_cast<f16x4*>(&Bs[cur ^ 1][bdo2]) = cvt4(rb2);
        *reinterpret_cast<f16x4*>(&Bs[cur ^ 1][bdo3]) = cvt4(rb3);
        __syncthreads();
        cur ^= 1;
    }
    compute(cur);

    #pragma unroll
    for (int fm = 0; fm < 4; ++fm) {
        #pragma unroll
        for (int reg = 0; reg < 4; ++reg) {
            int m = m_base + wm * 64 + fm * 16 + (lane >> 4) * 4 + reg;
            if (m < n_e) {
                int slot = off_e + m;
                int t = token_list[slot];
                float wt = weight_list[slot];
                float* orow = out + (size_t)t * H_DIM + n_base;
                #pragma unroll
                for (int fn = 0; fn < 4; ++fn) {
                    int col = wn * 64 + fn * 16 + (lane & 15);
                    atomicAdd(orow + col, wt * acc[fm][fn][reg]);
                }
            }
        }
    }
}

extern "C" void kernel_launch(void* const* d_in, const int* in_sizes, int n_in,
                              void* d_out, int out_size, void* d_ws, size_t ws_size,
                              hipStream_t stream) {
    const float* x  = (const float*)d_in[0];
    const float* wr = (const float*)d_in[1];
    const float* wg = (const float*)d_in[2];
    const float* wu = (const float*)d_in[3];
    const float* wd = (const float*)d_in[4];
    float* out = (float*)d_out;

    char* p = (char*)d_ws;
    auto carve = [&](size_t bytes) { char* q = p; p += (bytes + 255) & ~255ULL; return q; };
    _Float16* xh     = (_Float16*)carve((size_t)T_TOK * H_DIM * 2);
    _Float16* hbuf   = (_Float16*)carve((size_t)T_TOK * TOPK * I_DIM * 2);
    int*   topk_i    = (int*)  carve(T_TOK * TOPK * 4);
    float* topk_w    = (float*)carve(T_TOK * TOPK * 4);
    int*   tlist     = (int*)  carve(T_TOK * TOPK * 4);
    float* wlist     = (float*)carve(T_TOK * TOPK * 4);
    int*   counts    = (int*)  carve(E_NUM * 4);
    int*   offsets   = (int*)  carve(E_NUM * 4);
    int*   cursor    = (int*)  carve(E_NUM * 4);

    (void)hipMemsetAsync(d_out, 0, (size_t)out_size * 4, stream);
    (void)hipMemsetAsync(counts, 0, E_NUM * 4, stream);

    convert_x_kernel<<<(T_TOK * H_DIM) / (256 * 4), 256, 0, stream>>>(x, xh, T_TOK * H_DIM);
    router_topk_kernel<<<T_TOK, 64, 0, stream>>>(x, wr, topk_i, topk_w);
    count_kernel<<<(T_TOK * TOPK) / 256, 256, 0, stream>>>(topk_i, counts);
    scan_kernel<<<1, 64, 0, stream>>>(counts, offsets, cursor);
    scatter_kernel<<<(T_TOK * TOPK) / 256, 256, 0, stream>>>(topk_i, topk_w, cursor, tlist, wlist);
    gateup_kernel<<<GU_NWG, 256, 0, stream>>>(xh, wg, wu, offsets, counts, tlist, hbuf);
    down_kernel<<<DN_NWG, 256, 0, stream>>>(hbuf, wd, offsets, counts, tlist, wlist, out);
}